// Round 5
// baseline (247.389 us; speedup 1.0000x reference)
//
#include <hip/hip_runtime.h>

#define DD 256
#define KK 1024
#define HW 4096
#define NROWSZ 65536
#define OUT_Z 16777216
#define OUT_IDX OUT_Z
#define OUT_LOSS (OUT_Z + NROWSZ)

#define MARGIN 4.5e-4f

// ws layout (bytes)
#define WS_ESQ   0          // float[1024]
#define WS_EH    4096       // _Float16[262144] emb fp16 [k][d] (fallback B path)
#define WS_HLIST 528384     // int[65536]
#define WS_HCNT  790528     // int
#define WS_LSUM  790536     // double
#define WS_EMBT  791552     // float[256*1024] = 1 MB, emb^T [d][k]
#define WS_EHP   1840128    // _Float16 fragment-ordered emb: 512 KB

typedef _Float16 f16x8 __attribute__((ext_vector_type(8)));
typedef float f32x4 __attribute__((ext_vector_type(4)));
union U16x8 { uint4 u; f16x8 h; };
typedef unsigned long long u64;

static __device__ __forceinline__ u64 umin64(u64 a, u64 b) { return a < b ? a : b; }
static __device__ __forceinline__ unsigned pk16(float a, float b) {
    _Float16 ha = (_Float16)a, hb = (_Float16)b;
    return (unsigned)__builtin_bit_cast(unsigned short, ha)
         | ((unsigned)__builtin_bit_cast(unsigned short, hb) << 16);
}

// ---------------- prep: esq exact, eh fp16, embT fp32, ehP fragment-order ----------
__global__ void vq_prep(const float* __restrict__ emb, float* __restrict__ esq,
                        uint2* __restrict__ eh2, int* __restrict__ hcnt,
                        double* __restrict__ lsum, float* __restrict__ embT,
                        int use_embT, uint4* __restrict__ ehP, int use_ehp)
{
    const int bid = blockIdx.x;
    const int t = threadIdx.x;
    if (bid == 0 && t == 0) { *hcnt = 0; *lsum = 0.0; }

    if (bid < 4) {
        // esq: numpy pairwise-8 exact
        int k = bid * 256 + t;
        const float* e = emb + (size_t)k * DD;
        float blk[2];
#pragma unroll
        for (int b2 = 0; b2 < 2; ++b2) {
            const float* p = e + b2 * 128;
            float r[8];
#pragma unroll
            for (int j = 0; j < 8; ++j) r[j] = __fmul_rn(p[j], p[j]);
            for (int i = 8; i < 128; i += 8) {
#pragma unroll
                for (int j = 0; j < 8; ++j)
                    r[j] = __fadd_rn(r[j], __fmul_rn(p[i + j], p[i + j]));
            }
            blk[b2] = __fadd_rn(__fadd_rn(__fadd_rn(r[0], r[1]), __fadd_rn(r[2], r[3])),
                                __fadd_rn(__fadd_rn(r[4], r[5]), __fadd_rn(r[6], r[7])));
        }
        esq[k] = __fadd_rn(blk[0], blk[1]);
    } else if (bid < 20) {
        // eh fp16 [k][d] (fallback)
        int tid = (bid - 4) * 256 + t;
        const float4* e4 = (const float4*)emb;
#pragma unroll
        for (int i = 0; i < 16; ++i) {
            int idx = i * 4096 + tid;
            float4 v = e4[idx];
            eh2[idx] = make_uint2(pk16(v.x, v.y), pk16(v.z, v.w));
        }
    } else if (bid < 36) {
        // embT [d][k] fp32
        if (!use_embT) return;
        int u = bid - 20;
        int k = u * 64 + (t >> 2);
        int c = t & 3;
        const float4* e4 = (const float4*)(emb + (size_t)k * DD);
#pragma unroll
        for (int i = 0; i < 16; ++i) {
            float4 v = e4[c * 16 + i];
            int d = c * 64 + i * 4;
            embT[(size_t)(d + 0) * KK + k] = v.x;
            embT[(size_t)(d + 1) * KK + k] = v.y;
            embT[(size_t)(d + 2) * KK + k] = v.z;
            embT[(size_t)(d + 3) * KK + k] = v.w;
        }
    } else {
        // ehP: fragment-ordered fp16 B. uint4 index L = (t16*8 + ds)*64 + lane
        // holds eh[t16*16 + (lane&15)][ds*32 + (lane>>4)*8 .. +8]
        if (!use_ehp) return;
#pragma unroll
        for (int it = 0; it < 8; ++it) {
            int L = ((bid - 36) * 8 + it) * 256 + t;
            int lane = L & 63, ds = (L >> 6) & 7, t16 = L >> 9;
            int col = lane & 15, quad = lane >> 4;
            int code = t16 * 16 + col;
            int d0 = ds * 32 + quad * 8;
            const float* e = emb + (size_t)code * DD + d0;
            float4 a = *(const float4*)e;
            float4 c4 = *(const float4*)(e + 4);
            ehP[L] = make_uint4(pk16(a.x, a.y), pk16(a.z, a.w),
                                pk16(c4.x, c4.y), pk16(c4.z, c4.w));
        }
    }
}

// ---------------- score: 256-row tile; 8 waves x 32 rows; all codes per wave -------
// LDS: zh 128 KB (fp16 [256 rows][256 d], 16B-XOR swizzled) + esq 4 KB + cand 2 KB.
// B = linear 2KB/iter stream through ehP, identical addresses across all 8 waves
// (L1 broadcast); raw s_barrier every 8 tiles bounds wave drift for L1 reuse.
__launch_bounds__(512, 2)
__global__ void vq_score(const float* __restrict__ z, const _Float16* __restrict__ eh,
                         const uint4* __restrict__ ehP, const float* __restrict__ esq,
                         float* __restrict__ out, int* __restrict__ hlist,
                         int* __restrict__ hcnt, int use_ehp)
{
    __shared__ __align__(16) char zh[256 * 512];   // 128 KB
    __shared__ float esq_s[1024];
    __shared__ uint2 cand[256];

    const int t = threadIdx.x;
    const int lane = t & 63;
    const int w = t >> 6;           // 8 waves = 8 row groups of 32
    const int col = lane & 15;
    const int quad = lane >> 4;

    const int n0 = blockIdx.x * 256;
    const int b = n0 >> 12;
    const int hw0 = n0 & (HW - 1);

    // ---- stage z -> zh fp16: coalesced scalar loads (lane = row), uint4 swizzled
    {
        const int row = t & 255;        // waves 0-3: d-half 0; waves 4-7: d-half 1
        const int dh = t >> 8;
        const float* src = z + (size_t)b * DD * HW + hw0 + row;
#pragma unroll
        for (int i = 0; i < 16; ++i) {
            const int d0 = dh * 128 + i * 8;
            float v0 = src[(size_t)(d0 + 0) * HW];
            float v1 = src[(size_t)(d0 + 1) * HW];
            float v2 = src[(size_t)(d0 + 2) * HW];
            float v3 = src[(size_t)(d0 + 3) * HW];
            float v4 = src[(size_t)(d0 + 4) * HW];
            float v5 = src[(size_t)(d0 + 5) * HW];
            float v6 = src[(size_t)(d0 + 6) * HW];
            float v7 = src[(size_t)(d0 + 7) * HW];
            uint4 pk = make_uint4(pk16(v0, v1), pk16(v2, v3), pk16(v4, v5), pk16(v6, v7));
            *(uint4*)(zh + (size_t)row * 512 + ((d0 * 2) ^ ((row & 7) << 4))) = pk;
        }
        esq_s[t] = esq[t];
        esq_s[512 + t] = esq[512 + t];
    }
    __syncthreads();

    // ---- A-fragments: this wave's 32 rows (64 regs)
    U16x8 af[2][8];
#pragma unroll
    for (int nt = 0; nt < 2; ++nt) {
        const int row = w * 32 + nt * 16 + col;
        const int sw = (row & 7) << 4;
#pragma unroll
        for (int ds = 0; ds < 8; ++ds)
            af[nt][ds].u = *(const uint4*)(zh + (size_t)row * 512
                                           + ((ds * 64 + quad * 16) ^ sw));
    }

    unsigned t1[8], t2[8];
#pragma unroll
    for (int i = 0; i < 8; ++i) { t1[i] = 0xFFFFFFFFu; t2[i] = 0xFFFFFFFFu; }

    // process one 16-code tile with B-fragments already in registers
    auto proc = [&](U16x8 (&bf)[8], int t16) {
        const int code = t16 * 16 + col;
        const float eq1 = 1.0f + esq_s[code];
        f32x4 acc0 = (f32x4)0.0f, acc1 = (f32x4)0.0f;
#pragma unroll
        for (int ds = 0; ds < 8; ++ds) {
            acc0 = __builtin_amdgcn_mfma_f32_16x16x32_f16(af[0][ds].h, bf[ds].h, acc0, 0, 0, 0);
            acc1 = __builtin_amdgcn_mfma_f32_16x16x32_f16(af[1][ds].h, bf[ds].h, acc1, 0, 0, 0);
        }
#pragma unroll
        for (int r = 0; r < 4; ++r) {
            float s0 = fmaf(-2.0f, acc0[r], eq1);
            unsigned k0 = (__float_as_uint(s0) & 0xFFFFFC00u) | (unsigned)code;
            t2[r] = min(t2[r], max(t1[r], k0));
            t1[r] = min(t1[r], k0);
            float s1 = fmaf(-2.0f, acc1[r], eq1);
            unsigned k1 = (__float_as_uint(s1) & 0xFFFFFC00u) | (unsigned)code;
            t2[4 + r] = min(t2[4 + r], max(t1[4 + r], k1));
            t1[4 + r] = min(t1[4 + r], k1);
        }
    };

    if (use_ehp) {
        const uint4* bq = ehP + lane;   // [t16][ds][lane]: 2KB contiguous per t16
        U16x8 bfA[8], bfB[8];
#pragma unroll
        for (int ds = 0; ds < 8; ++ds) bfA[ds].u = bq[ds * 64];
#pragma unroll 1
        for (int t16 = 0; t16 < 64; t16 += 2) {
            const uint4* p1 = bq + (size_t)(t16 + 1) * 512;
#pragma unroll
            for (int ds = 0; ds < 8; ++ds) bfB[ds].u = p1[ds * 64];
            proc(bfA, t16);
            const uint4* p2 = bq + (size_t)((t16 + 2) & 63) * 512;  // wrap: harmless
#pragma unroll
            for (int ds = 0; ds < 8; ++ds) bfA[ds].u = p2[ds * 64];
            proc(bfB, t16 + 1);
            if ((t16 & 6) == 6) __builtin_amdgcn_s_barrier();  // bound wave drift
        }
    } else {
        const uint4* ehq = (const uint4*)eh;
#pragma unroll 1
        for (int t16 = 0; t16 < 64; ++t16) {
            const uint4* bp = ehq + (size_t)(t16 * 16 + col) * 32 + quad;
            U16x8 bf[8];
#pragma unroll
            for (int ds = 0; ds < 8; ++ds) bf[ds].u = bp[ds * 4];
            proc(bf, t16);
        }
    }

    // ---- cross-col (16-lane) top2 merge; each wave owns its 32 rows outright
#pragma unroll
    for (int mi = 0; mi < 8; ++mi) {
        unsigned a = t1[mi], bb = t2[mi];
#pragma unroll
        for (int off = 1; off < 16; off <<= 1) {
            unsigned o1 = __shfl_xor(a, off, 16);
            unsigned o2 = __shfl_xor(bb, off, 16);
            unsigned mx = max(a, o1);
            a = min(a, o1);
            bb = min(min(bb, o2), mx);
        }
        if (col == 0)
            cand[w * 32 + (mi >> 2) * 16 + quad * 4 + (mi & 3)] = make_uint2(a, bb);
    }
    __syncthreads();

    // ---- margin routing (idx only; hard rows -> hlist)
    if (t < 256) {
        uint2 c = cand[t];
        float s1 = __uint_as_float(c.x & 0xFFFFFC00u);
        float s2 = __uint_as_float(c.y & 0xFFFFFC00u);
        int k1 = (int)(c.x & 1023u);
        if (__fsub_rn(s2, s1) > MARGIN) {
            out[OUT_IDX + n0 + t] = (float)k1;
        } else {
            int pos = atomicAdd(hcnt, 1);
            hlist[pos] = n0 + t;
        }
    }
}

// ---- hard-path dot products (bit-exact sequential-d fma chain) --------------------
template<int USET>
static __device__ __forceinline__ void dot_codes(const float4* __restrict__ embT4,
                                                 const float4* __restrict__ emb4,
                                                 const float4* __restrict__ zb4,
                                                 int t, float (&acc_)[8][4])
{
#pragma unroll 2
    for (int dc = 0; dc < 64; ++dc) {
        float4 e0, e1, e2, e3;
        if (USET) {
            e0 = embT4[(size_t)(dc * 4 + 0) * 256 + t];
            e1 = embT4[(size_t)(dc * 4 + 1) * 256 + t];
            e2 = embT4[(size_t)(dc * 4 + 2) * 256 + t];
            e3 = embT4[(size_t)(dc * 4 + 3) * 256 + t];
        } else {
            float4 a0 = emb4[(size_t)(4 * t + 0) * 64 + dc];
            float4 a1 = emb4[(size_t)(4 * t + 1) * 64 + dc];
            float4 a2 = emb4[(size_t)(4 * t + 2) * 64 + dc];
            float4 a3 = emb4[(size_t)(4 * t + 3) * 64 + dc];
            e0 = make_float4(a0.x, a1.x, a2.x, a3.x);
            e1 = make_float4(a0.y, a1.y, a2.y, a3.y);
            e2 = make_float4(a0.z, a1.z, a2.z, a3.z);
            e3 = make_float4(a0.w, a1.w, a2.w, a3.w);
        }
#pragma unroll
        for (int j = 0; j < 8; ++j) {
            float4 zv = zb4[j * 64 + dc];
            acc_[j][0] = fmaf(zv.x, e0.x, acc_[j][0]);
            acc_[j][1] = fmaf(zv.x, e0.y, acc_[j][1]);
            acc_[j][2] = fmaf(zv.x, e0.z, acc_[j][2]);
            acc_[j][3] = fmaf(zv.x, e0.w, acc_[j][3]);
            acc_[j][0] = fmaf(zv.y, e1.x, acc_[j][0]);
            acc_[j][1] = fmaf(zv.y, e1.y, acc_[j][1]);
            acc_[j][2] = fmaf(zv.y, e1.z, acc_[j][2]);
            acc_[j][3] = fmaf(zv.y, e1.w, acc_[j][3]);
            acc_[j][0] = fmaf(zv.z, e2.x, acc_[j][0]);
            acc_[j][1] = fmaf(zv.z, e2.y, acc_[j][1]);
            acc_[j][2] = fmaf(zv.z, e2.z, acc_[j][2]);
            acc_[j][3] = fmaf(zv.z, e2.w, acc_[j][3]);
            acc_[j][0] = fmaf(zv.w, e3.x, acc_[j][0]);
            acc_[j][1] = fmaf(zv.w, e3.y, acc_[j][1]);
            acc_[j][2] = fmaf(zv.w, e3.z, acc_[j][2]);
            acc_[j][3] = fmaf(zv.w, e3.w, acc_[j][3]);
        }
    }
}

// ---------------- hard: exact fp32 rescan -> idx only ------------------------------
__launch_bounds__(256)
__global__ void vq_hard(const float* __restrict__ z, const float* __restrict__ emb,
                        const float* __restrict__ embT, const float* __restrict__ esq,
                        const int* __restrict__ hlist, const int* __restrict__ hcnt,
                        float* __restrict__ out, int use_embT)
{
    __shared__ __align__(16) float zbuf[8 * 256];
    __shared__ float chains[8][16];
    __shared__ float zq_s[8];
    __shared__ int rows_s[8];
    __shared__ u64 red[4][8];

    const int t = threadIdx.x;
    const int lane = t & 63;
    const int w = t >> 6;
    const int count = *hcnt;

    const float4* embT4 = (const float4*)embT;
    const float4* emb4 = (const float4*)emb;
    const float4* zb4 = (const float4*)zbuf;
    const float4 eqv4 = ((const float4*)esq)[t];
    const float eqa[4] = {eqv4.x, eqv4.y, eqv4.z, eqv4.w};

    for (int g = blockIdx.x; g * 8 < count; g += gridDim.x) {
        __syncthreads();
        if (t < 8) {
            int p = g * 8 + t;
            rows_s[t] = (p < count) ? hlist[p] : -1;
        }
        __syncthreads();

        {
            const int j = t >> 5, dpos = t & 31;
            const int r = rows_s[j];
            float4 v0 = make_float4(0.f, 0.f, 0.f, 0.f), v1 = v0;
            if (r >= 0) {
                const float* zp = z + (size_t)(r >> 12) * (DD * HW) + (r & (HW - 1));
                const int d0 = dpos * 8;
                v0.x = zp[(size_t)(d0 + 0) * HW];
                v0.y = zp[(size_t)(d0 + 1) * HW];
                v0.z = zp[(size_t)(d0 + 2) * HW];
                v0.w = zp[(size_t)(d0 + 3) * HW];
                v1.x = zp[(size_t)(d0 + 4) * HW];
                v1.y = zp[(size_t)(d0 + 5) * HW];
                v1.z = zp[(size_t)(d0 + 6) * HW];
                v1.w = zp[(size_t)(d0 + 7) * HW];
            }
            *(float4*)&zbuf[j * 256 + dpos * 8] = v0;
            *(float4*)&zbuf[j * 256 + dpos * 8 + 4] = v1;
        }
        __syncthreads();

        if (t < 128) {
            int j = t >> 4, c = t & 15, b2 = c >> 3, jj = c & 7;
            const float* p = &zbuf[j * 256];
            int base = b2 * 128 + jj;
            float v = p[base];
            float acc = __fmul_rn(v, v);
            for (int i = 1; i < 16; ++i) {
                float u = p[base + i * 8];
                acc = __fadd_rn(acc, __fmul_rn(u, u));
            }
            chains[j][c] = acc;
        }
        __syncthreads();
        if (t < 8) {
            const float* c = chains[t];
            float b0 = __fadd_rn(__fadd_rn(__fadd_rn(c[0], c[1]), __fadd_rn(c[2], c[3])),
                                 __fadd_rn(__fadd_rn(c[4], c[5]), __fadd_rn(c[6], c[7])));
            float b1 = __fadd_rn(__fadd_rn(__fadd_rn(c[8], c[9]), __fadd_rn(c[10], c[11])),
                                 __fadd_rn(__fadd_rn(c[12], c[13]), __fadd_rn(c[14], c[15])));
            zq_s[t] = __fadd_rn(b0, b1);
        }
        __syncthreads();

        float acc_[8][4];
#pragma unroll
        for (int j = 0; j < 8; ++j)
#pragma unroll
            for (int kk = 0; kk < 4; ++kk) acc_[j][kk] = 0.0f;

        if (use_embT) dot_codes<1>(embT4, emb4, zb4, t, acc_);
        else          dot_codes<0>(embT4, emb4, zb4, t, acc_);

#pragma unroll
        for (int j = 0; j < 8; ++j) {
            u64 m = ~0ull;
#pragma unroll
            for (int kk = 0; kk < 4; ++kk) {
                float s = __fsub_rn(__fadd_rn(zq_s[j], eqa[kk]),
                                    __fmul_rn(2.0f, acc_[j][kk]));
                u64 p = ((u64)__float_as_uint(s) << 32) | (unsigned)(4 * t + kk);
                m = umin64(m, p);
            }
#pragma unroll
            for (int off = 1; off < 64; off <<= 1)
                m = umin64(m, __shfl_xor(m, off, 64));
            if (lane == 0) red[w][j] = m;
        }
        __syncthreads();
        if (t < 8) {
            u64 m = umin64(umin64(red[0][t], red[1][t]), umin64(red[2][t], red[3][t]));
            int r = rows_s[t];
            if (r >= 0) out[OUT_IDX + r] = (float)(int)(m & 0xffffffffu);
        }
    }
}

// ---------------- out: d-major contiguous scatter + loss for ALL rows --------------
__launch_bounds__(256)
__global__ void vq_out(const float* __restrict__ z, const float* __restrict__ emb,
                       const float* __restrict__ embT, float* out,
                       double* __restrict__ lsum, int use_embT)
{
    __shared__ float et[8 * 1024];   // embT rows [dg*8 .. +8)
    __shared__ float wsum[4];

    const int t = threadIdx.x;
    const int lane = t & 63;
    const int w = t >> 6;
    const int bb = blockIdx.x >> 5;     // batch
    const int dg = blockIdx.x & 31;     // d-group (8 d)

    if (use_embT) {
#pragma unroll
        for (int c = 0; c < 8; ++c)
            *(float4*)&et[c * 1024 + t * 4] =
                *(const float4*)&embT[(size_t)(dg * 8 + c) * KK + t * 4];
    } else {
        for (int i = 0; i < 32; ++i) {
            int kk = i * 256 + t;
            et[kk] = emb[(size_t)(kk & 1023) * DD + dg * 8 + (kk >> 10)];
        }
    }
    __syncthreads();

    float lacc = 0.f;
    const size_t zb = (size_t)bb * DD * HW;
    const float* idxf = out + OUT_IDX + (size_t)bb * HW;
#pragma unroll
    for (int ch = 0; ch < 4; ++ch) {
        const int hw = ch * 1024 + t * 4;
        float4 fi = *(const float4*)&idxf[hw];
        int k0 = (int)fi.x, k1 = (int)fi.y, k2 = (int)fi.z, k3 = (int)fi.w;
#pragma unroll
        for (int dl = 0; dl < 8; ++dl) {
            size_t off = zb + (size_t)(dg * 8 + dl) * HW + hw;
            float4 zv = *(const float4*)&z[off];
            float4 e;
            e.x = et[dl * 1024 + k0];
            e.y = et[dl * 1024 + k1];
            e.z = et[dl * 1024 + k2];
            e.w = et[dl * 1024 + k3];
            *(float4*)&out[off] = e;
            float df;
            df = e.x - zv.x; lacc = fmaf(df, df, lacc);
            df = e.y - zv.y; lacc = fmaf(df, df, lacc);
            df = e.z - zv.z; lacc = fmaf(df, df, lacc);
            df = e.w - zv.w; lacc = fmaf(df, df, lacc);
        }
    }
#pragma unroll
    for (int off = 32; off > 0; off >>= 1) lacc += __shfl_down(lacc, off, 64);
    if (lane == 0) wsum[w] = lacc;
    __syncthreads();
    if (t == 0) {
        double tot = (double)wsum[0] + (double)wsum[1] + (double)wsum[2] + (double)wsum[3];
        atomicAdd(lsum, tot);
    }
}

__global__ void vq_final(const double* __restrict__ lsum, float* __restrict__ out)
{
    out[OUT_LOSS] = (float)(0.25 * (lsum[0] / (double)OUT_Z));
}

extern "C" void kernel_launch(void* const* d_in, const int* in_sizes, int n_in,
                              void* d_out, int out_size, void* d_ws, size_t ws_size,
                              hipStream_t stream)
{
    const float* z = (const float*)d_in[0];
    const float* emb = (const float*)d_in[1];
    float* out = (float*)d_out;
    char* w = (char*)d_ws;

    float* esq = (float*)(w + WS_ESQ);
    _Float16* eh = (_Float16*)(w + WS_EH);
    uint2* eh2 = (uint2*)(w + WS_EH);
    int* hlist = (int*)(w + WS_HLIST);
    int* hcnt = (int*)(w + WS_HCNT);
    double* lsum = (double*)(w + WS_LSUM);
    float* embT = (float*)(w + WS_EMBT);
    uint4* ehP = (uint4*)(w + WS_EHP);

    int use_embT = (ws_size >= (size_t)WS_EMBT + (size_t)DD * KK * sizeof(float)) ? 1 : 0;
    int use_ehp = (ws_size >= (size_t)WS_EHP + (size_t)KK * DD * sizeof(_Float16)) ? 1 : 0;

    vq_prep<<<dim3(52), dim3(256), 0, stream>>>(emb, esq, eh2, hcnt, lsum, embT, use_embT,
                                                ehP, use_ehp);
    vq_score<<<dim3(256), dim3(512), 0, stream>>>(z, eh, ehP, esq, out, hlist, hcnt,
                                                  use_ehp);
    vq_hard<<<dim3(1024), dim3(256), 0, stream>>>(z, emb, embT, esq, hlist, hcnt, out,
                                                  use_embT);
    vq_out<<<dim3(512), dim3(256), 0, stream>>>(z, emb, embT, out, lsum, use_embT);
    vq_final<<<dim3(1), dim3(1), 0, stream>>>(lsum, out);
}